// Round 7
// baseline (574.495 us; speedup 1.0000x reference)
//
#include <hip/hip_runtime.h>

typedef __attribute__((ext_vector_type(8))) short bf16x8;
typedef __attribute__((ext_vector_type(4))) float f32x4;
typedef __attribute__((ext_vector_type(16))) float f32x16;
typedef __attribute__((ext_vector_type(2))) unsigned int u32x2;

constexpr int B_ = 8, Q_ = 512, HIST_ = 1536, HID_ = 4096, NH_ = 32, D_ = 128;
constexpr int BS_ = 64, NBLK_ = 32;
constexpr int T_ = B_ * Q_;            // 4096
constexpr int QKVN = (NH_ + 2) * D_;   // 4352
constexpr int KVC = NBLK_ * BS_;       // 2048

__device__ __forceinline__ unsigned short f2bf(float f) {
  union { float f; unsigned u; } v; v.f = f;
  unsigned r = v.u + 0x7FFFu + ((v.u >> 16) & 1u);
  return (unsigned short)(r >> 16);
}
__device__ __forceinline__ float bf2f(unsigned short s) {
  union { unsigned u; float f; } v; v.u = ((unsigned)s) << 16;
  return v.f;
}
__device__ __forceinline__ int cvtpk_bf16(float lo, float hi) {
  int r;
  asm("v_cvt_pk_bf16_f32 %0, %1, %2" : "=v"(r) : "v"(lo), "v"(hi));
  return r;
}

// ---------------- f32 -> bf16 conversion (vectorized) ----------------
__global__ void k_conv(const float* __restrict__ in, unsigned short* __restrict__ out, int n4) {
  int i = blockIdx.x * blockDim.x + threadIdx.x;
  int stride = gridDim.x * blockDim.x;
  for (; i < n4; i += stride) {
    float4 v = reinterpret_cast<const float4*>(in)[i];
    ushort4 o;
    o.x = f2bf(v.x); o.y = f2bf(v.y); o.z = f2bf(v.z); o.w = f2bf(v.w);
    reinterpret_cast<ushort4*>(out)[i] = o;
  }
}

// ---------------- bf16 GEMM: 128x256 tile, BK=32, 3-buf ring, 2 blocks/CU ----------------
// C[i,j] = sum_k A[i,k]*B[j,k]. 8 waves (2M x 4N), 512 thr, 72 KiB LDS (3 x 24 KiB).
// Per K-step: stage(t+2) -> 8 ds_read_b128 -> 16 MFMA -> vmcnt(3) (drains t+1's
// loads, leaves t+2 in flight: slack = 2 K-steps) -> one raw barrier.
// Cross-block TLP (2 blocks/CU) hides the residual latency, like k_attn.
// Bank swizzle: slot ^= (row&3)^((row>>2)&3) on 16B slots of 64B rows -> <=2-way (free).
#define SW_(r) ((((r) & 3)) ^ (((r) >> 2) & 3))

__global__ __launch_bounds__(512, 4) void k_gemm(const unsigned short* __restrict__ A,
                          const unsigned short* __restrict__ Bm,
                          float* __restrict__ Cf, unsigned short* __restrict__ Cb,
                          int MB, int K, int ldc) {
  extern __shared__ unsigned short smem[];
  unsigned short* sA = smem;            // 3 bufs x 4096 shorts (128 rows x 32 k)
  unsigned short* sB = smem + 12288;    // 3 bufs x 8192 shorts (256 rows x 32 k)
  const int tid = threadIdx.x, lane = tid & 63, w = tid >> 6;
  const int wr = w >> 2, wc = w & 3;
  const int lr = lane & 15, lk = lane >> 4;

  // bijective XCD swizzle (m204)
  const int nwg = gridDim.x, orig = blockIdx.x;
  const int q8 = nwg >> 3, r8 = nwg & 7, xcd = orig & 7;
  const int wg = (xcd < r8 ? xcd * (q8 + 1) : r8 * (q8 + 1) + (xcd - r8) * q8) + (orig >> 3);
  const int m0 = (wg % MB) * 128;
  const int n0 = (wg / MB) * 256;
  const int NT = K >> 5;

  f32x4 acc[4][4];
#pragma unroll
  for (int m = 0; m < 4; ++m)
#pragma unroll
    for (int n = 0; n < 4; ++n) acc[m][n] = f32x4{0.f, 0.f, 0.f, 0.f};

  // stage one 24 KiB K-step (A 8 KiB + B 16 KiB): linear LDS dest, inverse-swizzled source
  auto stage = [&](int bi, int k0) {
    {
      const int ob = tid << 4;           // byte off in A buf
      const int row = ob >> 6;           // 0..127
      const int s = (ob >> 4) & 3;
      const unsigned short* src = A + (size_t)(m0 + row) * K + k0 + ((s ^ SW_(row)) << 3);
      __builtin_amdgcn_global_load_lds((const __attribute__((address_space(1))) void*)src,
          (__attribute__((address_space(3))) void*)((char*)sA + bi * 8192 + (tid << 4)), 16, 0, 0);
    }
#pragma unroll
    for (int c = 0; c < 2; ++c) {
      const int u = (c << 9) + tid;
      const int ob = u << 4;             // byte off in B buf
      const int row = ob >> 6;           // 0..255
      const int s = (ob >> 4) & 3;
      const unsigned short* src = Bm + (size_t)(n0 + row) * K + k0 + ((s ^ SW_(row)) << 3);
      __builtin_amdgcn_global_load_lds((const __attribute__((address_space(1))) void*)src,
          (__attribute__((address_space(3))) void*)((char*)sB + bi * 16384 + (ob)), 16, 0, 0);
    }
  };

  // prologue: stage K-steps 0 and 1; drain step 0 (leave step 1's 3 loads in flight)
  stage(0, 0);
  stage(1, NT > 1 ? 32 : 0);
  asm volatile("s_waitcnt vmcnt(3)" ::: "memory");
  __builtin_amdgcn_s_barrier();
  asm volatile("" ::: "memory");

  int cur = 0;
  for (int t = 0; t < NT; ++t) {
    int sb = cur + 2; if (sb > 2) sb -= 3;
    const int ts = (t + 2 < NT) ? (t + 2) : (NT - 1);  // clamp keeps vmcnt ledger invariant
    stage(sb, ts << 5);

    const unsigned short* a_t = sA + cur * 4096;
    const unsigned short* b_t = sB + cur * 8192;
    bf16x8 af[4], bfr[4];
#pragma unroll
    for (int m = 0; m < 4; ++m) {
      const int r = wr * 64 + m * 16 + lr;
      af[m] = *reinterpret_cast<const bf16x8*>(&a_t[r * 32 + ((lk ^ SW_(r)) << 3)]);
    }
#pragma unroll
    for (int n = 0; n < 4; ++n) {
      const int r = wc * 64 + n * 16 + lr;
      bfr[n] = *reinterpret_cast<const bf16x8*>(&b_t[r * 32 + ((lk ^ SW_(r)) << 3)]);
    }
    __builtin_amdgcn_s_setprio(1);
#pragma unroll
    for (int m = 0; m < 4; ++m)
#pragma unroll
      for (int n = 0; n < 4; ++n)
        acc[m][n] = __builtin_amdgcn_mfma_f32_16x16x32_bf16(af[m], bfr[n], acc[m][n], 0, 0, 0);
    __builtin_amdgcn_s_setprio(0);

    asm volatile("s_waitcnt vmcnt(3)" ::: "memory");
    __builtin_amdgcn_s_barrier();
    asm volatile("" ::: "memory");
    cur = (cur == 2) ? 0 : cur + 1;
  }
  // drain in-flight gload_lds before LDS is released to the next block
  asm volatile("s_waitcnt vmcnt(0)" ::: "memory");

#pragma unroll
  for (int m = 0; m < 4; ++m)
#pragma unroll
    for (int n = 0; n < 4; ++n)
#pragma unroll
      for (int j = 0; j < 4; ++j) {
        const int rr = m0 + wr * 64 + m * 16 + lk * 4 + j;
        const int cc = n0 + wc * 64 + n * 16 + lr;
        if (Cb) Cb[(size_t)rr * ldc + cc] = f2bf(acc[m][n][j]);
        else Cf[(size_t)rr * ldc + cc] = acc[m][n][j];
      }
}

// ---------------- RoPE + repack: fused(T,4352) -> q (pre-scaled by log2e/sqrt(d)), kseq[b,kv,d], vtg[b,d,kv] ----------------
__global__ void k_rope(const unsigned short* __restrict__ fused,
                       const int* __restrict__ pos_ids,
                       unsigned short* __restrict__ qb,
                       unsigned short* __restrict__ kseq,
                       unsigned short* __restrict__ vtg) {
  int t = blockIdx.x;
  int d = threadIdx.x;  // 128 threads
  int b = t >> 9, q = t & 511;
  int pos = pos_ids[t];
  __shared__ float cs[64], sn[64];
  if (d < 64) {
    float inv = powf(10000.f, -(float)d * (1.f / 64.f));
    float ang = (float)pos * inv;
    cs[d] = cosf(ang);
    sn[d] = sinf(ang);
  }
  __syncthreads();
  // 1/sqrt(128) * log2(e): attention uses exp2
  const float scale = 0.1275174313836907f;
  float c = cs[d & 63], s = sn[d & 63];
  const unsigned short* row = fused + (size_t)t * QKVN;
#pragma unroll 4
  for (int h = 0; h < NH_; ++h) {
    float x = bf2f(row[h * D_ + d]);
    float xr = (d < 64) ? -bf2f(row[h * D_ + d + 64]) : bf2f(row[h * D_ + d - 64]);
    qb[(((size_t)(b * NH_ + h)) * Q_ + q) * D_ + d] = f2bf((x * c + xr * s) * scale);
  }
  {
    float x = bf2f(row[NH_ * D_ + d]);
    float xr = (d < 64) ? -bf2f(row[NH_ * D_ + d + 64]) : bf2f(row[NH_ * D_ + d - 64]);
    kseq[((size_t)b * KVC + pos) * D_ + d] = f2bf(x * c + xr * s);
  }
  vtg[((size_t)b * D_ + d) * KVC + pos] = row[(NH_ + 1) * D_ + d];
}

// ---------------- gather history KV: paged f32 cache -> kseq (row-major) + vtg (transposed) ----------------
__global__ void k_gather(const float* __restrict__ pk, const float* __restrict__ pv,
                         const int* __restrict__ bo,
                         unsigned short* __restrict__ kseq, unsigned short* __restrict__ vtg) {
  __shared__ unsigned short vl[64 * 140];
  const int ptile = blockIdx.x;              // B_ * (HIST_/64) = 192
  const int b = ptile / (HIST_ / 64);
  const int p0 = (ptile % (HIST_ / 64)) * 64;
  const int tid = threadIdx.x;
  const int blk = bo[b * NBLK_ + (p0 >> 6)];
#pragma unroll
  for (int c = 0; c < 8; ++c) {
    int u = c * 256 + tid;  // 64 p x 32 d4
    int p = u >> 5, d4 = u & 31;
    size_t src = ((size_t)blk * BS_ + p) * D_ + d4 * 4;
    float4 kv = *reinterpret_cast<const float4*>(pk + src);
    ushort4 ko;
    ko.x = f2bf(kv.x); ko.y = f2bf(kv.y); ko.z = f2bf(kv.z); ko.w = f2bf(kv.w);
    *reinterpret_cast<ushort4*>(kseq + ((size_t)b * KVC + p0 + p) * D_ + d4 * 4) = ko;
    float4 vv = *reinterpret_cast<const float4*>(pv + src);
    ushort4 vo;
    vo.x = f2bf(vv.x); vo.y = f2bf(vv.y); vo.z = f2bf(vv.z); vo.w = f2bf(vv.w);
    *reinterpret_cast<ushort4*>(&vl[p * 140 + d4 * 4]) = vo;
  }
  __syncthreads();
#pragma unroll
  for (int c = 0; c < 4; ++c) {
    int u = c * 256 + tid;  // 128 d x 8 pg
    int d = u >> 3, pg = u & 7;
    bf16x8 vv8;
#pragma unroll
    for (int i = 0; i < 8; ++i) vv8[i] = (short)vl[(pg * 8 + i) * 140 + d];
    *reinterpret_cast<bf16x8*>(vtg + ((size_t)b * D_ + d) * KVC + p0 + pg * 8) = vv8;
  }
}

// ---------------- MQA flash attention, 8-wave swapped-QK^T (m214/T12 structure) ----------------
__global__ __launch_bounds__(512, 2) void k_attn(const unsigned short* __restrict__ qb,
                       const unsigned short* __restrict__ kseq,
                       const unsigned short* __restrict__ vtg,
                       const int* __restrict__ histL,
                       unsigned short* __restrict__ outb) {
  __shared__ alignas(16) unsigned short kl[2][64 * 128];  // [kv 64][d 128], slot^=(row&15)
  __shared__ alignas(16) unsigned short vt[2][128 * 64];  // [d 128][kv 64], slot^=(row&7)
  const int qt = blockIdx.x, hp = blockIdx.y, b = blockIdx.z;
  const int tid = threadIdx.x, lane = tid & 63, w = tid >> 6;
  const int H = lane >> 5, q = lane & 31;
  const int h = hp * 8 + w;
  const int q0 = qt * 32;
  const int hist = histL[b];
  const unsigned short* kseq_b = kseq + (size_t)b * KVC * D_;
  const unsigned short* vtg_b  = vtg + (size_t)b * D_ * KVC;

  const unsigned short* qrow = qb + (((size_t)(b * NH_ + h)) * Q_ + q0 + q) * D_;
  bf16x8 aq[8];
#pragma unroll
  for (int ds = 0; ds < 8; ++ds)
    aq[ds] = *reinterpret_cast<const bf16x8*>(qrow + ds * 16 + H * 8);

  f32x16 o[4];
#pragma unroll
  for (int db = 0; db < 4; ++db)
#pragma unroll
    for (int r = 0; r < 16; ++r) o[db][r] = 0.f;
  float m = -1e30f, l = 0.f;

  const int ntiles = (hist + q0 + 32 + 63) >> 6;

  auto STAGE = [&](int bufi, int kv0) {
#pragma unroll
    for (int c = 0; c < 2; ++c) {
      int ob = c * 8192 + tid * 16;
      int row = ob >> 8;
      int sp = (ob >> 4) & 15;
      const unsigned short* src = kseq_b + (size_t)(kv0 + row) * D_ + (((sp ^ (row & 15)) << 3));
      __builtin_amdgcn_global_load_lds((const __attribute__((address_space(1))) void*)src,
          (__attribute__((address_space(3))) void*)(&kl[bufi][c * 4096 + w * 512]), 16, 0, 0);
    }
#pragma unroll
    for (int c = 0; c < 2; ++c) {
      int ob = c * 8192 + tid * 16;
      int row = ob >> 7;
      int sp = (ob >> 4) & 7;
      const unsigned short* src = vtg_b + (size_t)row * KVC + kv0 + (((sp ^ (row & 7)) << 3));
      __builtin_amdgcn_global_load_lds((const __attribute__((address_space(1))) void*)src,
          (__attribute__((address_space(3))) void*)(&vt[bufi][c * 4096 + w * 512]), 16, 0, 0);
    }
  };

  STAGE(0, 0);
  __syncthreads();

  for (int it = 0; it < ntiles; ++it) {
    const int cur = it & 1;
    if (it + 1 < ntiles) STAGE(cur ^ 1, (it + 1) * 64);
    const unsigned short* kb = kl[cur];
    const unsigned short* vb = vt[cur];

    f32x16 sa = f32x16{0.f,0.f,0.f,0.f,0.f,0.f,0.f,0.f,0.f,0.f,0.f,0.f,0.f,0.f,0.f,0.f};
    f32x16 sb = sa, sc = sa, sd = sa;
#pragma unroll
    for (int ds = 0; ds < 4; ++ds) {
      const int sl = ((2 * ds + H) ^ (q & 15)) << 3;
      bf16x8 k0 = *reinterpret_cast<const bf16x8*>(kb + q * 128 + sl);
      bf16x8 k1 = *reinterpret_cast<const bf16x8*>(kb + (32 + q) * 128 + sl);
      sa = __builtin_amdgcn_mfma_f32_32x32x16_bf16(k0, aq[ds], sa, 0, 0, 0);
      sc = __builtin_amdgcn_mfma_f32_32x32x16_bf16(k1, aq[ds], sc, 0, 0, 0);
    }
#pragma unroll
    for (int ds = 4; ds < 8; ++ds) {
      const int sl = ((2 * ds + H) ^ (q & 15)) << 3;
      bf16x8 k0 = *reinterpret_cast<const bf16x8*>(kb + q * 128 + sl);
      bf16x8 k1 = *reinterpret_cast<const bf16x8*>(kb + (32 + q) * 128 + sl);
      sb = __builtin_amdgcn_mfma_f32_32x32x16_bf16(k0, aq[ds], sb, 0, 0, 0);
      sd = __builtin_amdgcn_mfma_f32_32x32x16_bf16(k1, aq[ds], sd, 0, 0, 0);
    }
    f32x16 s0 = sa + sb;
    f32x16 s1 = sc + sd;

    if (it == ntiles - 1) {
      const int limit = hist + q0 + q - it * 64 - 4 * H;
#pragma unroll
      for (int r = 0; r < 16; ++r) {
        const int koff = (r & 3) + 8 * ((r >> 2) & 1) + 16 * (r >> 3);
        if (koff > limit) s0[r] = -1e30f;
        if (32 + koff > limit) s1[r] = -1e30f;
      }
    }

    float pmax = s0[0];
#pragma unroll
    for (int r = 1; r < 16; ++r) pmax = fmaxf(pmax, s0[r]);
#pragma unroll
    for (int r = 0; r < 16; ++r) pmax = fmaxf(pmax, s1[r]);
    pmax = fmaxf(pmax, __shfl_xor(pmax, 32));
    if (__any(pmax > m + 11.54f)) {
      float mn = fmaxf(m, pmax);
      float al = exp2f(m - mn);
      m = mn;
      l *= al;
#pragma unroll
      for (int db = 0; db < 4; ++db)
#pragma unroll
        for (int r = 0; r < 16; ++r) o[db][r] *= al;
    }
    float rs = 0.f;
#pragma unroll
    for (int r = 0; r < 16; ++r) { s0[r] = exp2f(s0[r] - m); rs += s0[r]; }
#pragma unroll
    for (int r = 0; r < 16; ++r) { s1[r] = exp2f(s1[r] - m); rs += s1[r]; }
    rs += __shfl_xor(rs, 32);
    l += rs;

#pragma unroll
    for (int s = 0; s < 4; ++s) {
      float p0, p1, p2, p3, p4, p5, p6, p7;
      if (s == 0)      { p0=s0[0];p1=s0[1];p2=s0[2];p3=s0[3];p4=s0[4];p5=s0[5];p6=s0[6];p7=s0[7]; }
      else if (s == 1) { p0=s0[8];p1=s0[9];p2=s0[10];p3=s0[11];p4=s0[12];p5=s0[13];p6=s0[14];p7=s0[15]; }
      else if (s == 2) { p0=s1[0];p1=s1[1];p2=s1[2];p3=s1[3];p4=s1[4];p5=s1[5];p6=s1[6];p7=s1[7]; }
      else             { p0=s1[8];p1=s1[9];p2=s1[10];p3=s1[11];p4=s1[12];p5=s1[13];p6=s1[14];p7=s1[15]; }
      int c01 = cvtpk_bf16(p0, p1);
      int c23 = cvtpk_bf16(p2, p3);
      int c45 = cvtpk_bf16(p4, p5);
      int c67 = cvtpk_bf16(p6, p7);
      u32x2 rA = __builtin_amdgcn_permlane32_swap(c01, c45, false, false);
      u32x2 rB = __builtin_amdgcn_permlane32_swap(c23, c67, false, false);
      union { unsigned wds[4]; bf16x8 v; } uu;
      uu.wds[0] = rA[0]; uu.wds[1] = rB[0]; uu.wds[2] = rA[1]; uu.wds[3] = rB[1];
#pragma unroll
      for (int db = 0; db < 4; ++db) {
        const int row = db * 32 + q;
        bf16x8 vf = *reinterpret_cast<const bf16x8*>(vb + row * 64 + ((((2 * s + H) ^ (row & 7))) << 3));
        o[db] = __builtin_amdgcn_mfma_f32_32x32x16_bf16(vf, uu.v, o[db], 0, 0, 0);
      }
    }
    __syncthreads();
  }

  const float il = 1.f / l;
  unsigned short* orow = outb + (size_t)(b * Q_ + q0 + q) * (NH_ * D_) + h * D_;
#pragma unroll
  for (int db = 0; db < 4; ++db)
#pragma unroll
    for (int rr = 0; rr < 4; ++rr) {
      ushort4 st;
      st.x = f2bf(o[db][rr * 4 + 0] * il);
      st.y = f2bf(o[db][rr * 4 + 1] * il);
      st.z = f2bf(o[db][rr * 4 + 2] * il);
      st.w = f2bf(o[db][rr * 4 + 3] * il);
      *reinterpret_cast<ushort4*>(orow + db * 32 + rr * 8 + 4 * H) = st;
    }
}

extern "C" void kernel_launch(void* const* d_in, const int* in_sizes, int n_in,
                              void* d_out, int out_size, void* d_ws, size_t ws_size,
                              hipStream_t stream) {
  const float* hidden = (const float*)d_in[0];
  const float* qkvw   = (const float*)d_in[1];
  const float* densew = (const float*)d_in[2];
  const float* pk     = (const float*)d_in[3];
  const float* pv     = (const float*)d_in[4];
  const int* histL    = (const int*)d_in[7];
  const int* bo       = (const int*)d_in[8];
  const int* posids   = (const int*)d_in[9];
  float* out = (float*)d_out;

  char* ws = (char*)d_ws;
  unsigned short* ws_hidden = (unsigned short*)(ws);                    // 33.5 MB
  unsigned short* ws_w      = (unsigned short*)(ws + 33554432);         // 35.7 MB
  unsigned short* ws_fused  = (unsigned short*)(ws + 69206016);         // 35.7 MB
  unsigned short* ws_q      = (unsigned short*)(ws + 104857600);        // 33.5 MB
  unsigned short* ws_k      = (unsigned short*)(ws + 138412032);        // 4.2 MB
  unsigned short* ws_vt     = (unsigned short*)(ws + 142606336);        // 4.2 MB (transposed V)
  unsigned short* ws_attn   = ws_hidden;                                // reuse after GEMM1

  k_conv<<<2048, 256, 0, stream>>>(hidden, ws_hidden, T_ * HID_ / 4);
  k_conv<<<2048, 256, 0, stream>>>(qkvw, ws_w, QKVN * HID_ / 4);
  k_gemm<<<dim3((T_ / 128) * (QKVN / 256)), 512, 73728, stream>>>(
      ws_hidden, ws_w, nullptr, ws_fused, T_ / 128, HID_, QKVN);
  k_rope<<<T_, 128, 0, stream>>>(ws_fused, posids, ws_q, ws_k, ws_vt);
  k_gather<<<B_ * (HIST_ / 64), 256, 0, stream>>>(pk, pv, bo, ws_k, ws_vt);
  dim3 ga(Q_ / 32, NH_ / 8, B_);
  k_attn<<<ga, 512, 0, stream>>>(ws_q, ws_k, ws_vt, histL, ws_attn);
  k_conv<<<2048, 256, 0, stream>>>(densew, ws_w, HID_ * HID_ / 4);
  k_gemm<<<dim3((T_ / 128) * (HID_ / 256)), 512, 73728, stream>>>(
      ws_attn, ws_w, out, nullptr, T_ / 128, HID_, HID_);
}